// Round 15
// baseline (392.397 us; speedup 1.0000x reference)
//
#include <hip/hip_runtime.h>
#include <hip/hip_bf16.h>
#include <math.h>

#define NB 8
#define NN 8192
#define ND 1024
#define NH 256
#define NC 2
#define M_ALL (NB * NN)   // 65536 rows
#define BM 128            // block tile rows
#define TPB 64            // tiles per bag (8192/128)
#define BK 64             // K per iteration (2 MFMA k-steps)
#define NT (ND / BK)      // 16 iterations
#define PSTRIDE 260       // per-tile partial: 256 pooled + m_t + l_t (+pad)

typedef __attribute__((ext_vector_type(8))) short bf16x8;
typedef __attribute__((ext_vector_type(4))) float f32x4;

// barrier WITHOUT the compiler's vmcnt(0) drain: LDS ordering only.
#define BARRIER_LGKM() asm volatile("s_waitcnt lgkmcnt(0)\n\ts_barrier" ::: "memory")

__device__ inline unsigned short f2bf(float f) {   // RNE float -> bf16 bits
    unsigned int u = __builtin_bit_cast(unsigned int, f);
    u += 0x7FFFu + ((u >> 16) & 1u);
    return (unsigned short)(u >> 16);
}
__device__ inline float bf2f(unsigned short s) {
    unsigned int u = ((unsigned int)s) << 16;
    return __builtin_bit_cast(float, u);
}
__device__ inline unsigned int pk_bf16(float a, float b) {  // low=a, high=b
    __hip_bfloat162 t = __float22bfloat162_rn(float2{a, b});
    unsigned int r;
    __builtin_memcpy(&r, &t, 4);
    return r;
}

__device__ inline float wave_reduce_sum(float v) {
#pragma unroll
    for (int off = 32; off > 0; off >>= 1) v += __shfl_down(v, off, 64);
    return v;
}
__device__ inline float wave_reduce_max(float v) {
#pragma unroll
    for (int off = 32; off > 0; off >>= 1) v = fmaxf(v, __shfl_down(v, off, 64));
    return v;
}

// ---------------------------------------------------------------------------
// Pack Wp into bf16 hi/lo, MFMA-B-fragment-contiguous:
// frag (t = kstep 0..31, f = col-frag 0..15), lane l holds
// B[k = t*32 + (l>>4)*8 + j][col = f*16 + (l&15)], j=0..7 contiguous.
// ---------------------------------------------------------------------------
__global__ void pack_kernel(const float* __restrict__ Wp,
                            unsigned short* __restrict__ hi,
                            unsigned short* __restrict__ lo)
{
    int idx  = blockIdx.x * 256 + threadIdx.x;   // 0..32767
    int lane = idx & 63;
    int f    = (idx >> 6) & 15;
    int t    = idx >> 10;
    int col  = f * 16 + (lane & 15);
    int k0   = t * 32 + (lane >> 4) * 8;
    size_t off = (size_t)idx * 8;
#pragma unroll
    for (int j = 0; j < 8; ++j) {
        float w = Wp[(size_t)(k0 + j) * NH + col];
        unsigned short h = f2bf(w);
        hi[off + j] = h;
        lo[off + j] = f2bf(w - bf2f(h));
    }
}

// ---------------------------------------------------------------------------
// Fused GEMM + SiLU + attention logit + flash-style tile pooling.
// vs R13: BM 256->128 => grid 512 (~320 live after ragged exit) => 2-4
// INDEPENDENT blocks per CU (32 KB LDS, ~190 regs/wave) -- stalls of one
// block hide under another's MFMAs instead of lockstep-coinciding. Dual B
// register sets (affordable at acc[4][4]) remove the per-k-step WAR hazard.
// Numerics identical: bf16 hi+lo W, x RNE-bf16, fp32 h pooling.
// ---------------------------------------------------------------------------
__global__ __launch_bounds__(512, 4)
void gemm_kernel(const float* __restrict__ x,
                 const unsigned short* __restrict__ Bhi,
                 const unsigned short* __restrict__ Blo,
                 const float* __restrict__ bp,
                 const float* __restrict__ Wa,
                 const float* __restrict__ ba,
                 const int* __restrict__ lengths,
                 float* __restrict__ part)
{
    __shared__ __align__(16) unsigned char lds_raw[32768];  // A dbuf 2x16KB; epilogue overlay

    const int tid  = threadIdx.x;
    const int wave = tid >> 6;
    const int lane = tid & 63;
    const int wr = wave >> 2;           // 0..1: 64-row group
    const int wc = wave & 3;            // 0..3: 64-col group
    const int blk = blockIdx.x;
    const size_t row0 = (size_t)blk * BM;

    // ragged early-exit
    const int bag   = blk >> 6;                // 64 tiles per bag
    const int tile  = blk & 63;
    const int lrow0 = tile * BM;
    const int len   = lengths[bag];
    if (lrow0 >= len) return;

    // ---- x staging: thread -> row (tid>>2), 16-float slot (tid&3)
    const int srow = tid >> 2;                 // 0..127
    const int slot = tid & 3;
    const float* xp = x + (row0 + srow) * ND + slot * 16;
    const int swz = (srow & 7) << 4;
    const int woff0 = (slot * 32) ^ swz;
    const int woff1 = (slot * 32 + 16) ^ swz;
    char* const wrow = (char*)lds_raw + srow * 128;

    float4 gx[4];                              // 16 VGPR, 1-iter lifetime
    auto issueX = [&](int t) {
        const float4* p = (const float4*)(xp + (size_t)t * BK);
#pragma unroll
        for (int i = 0; i < 4; ++i) gx[i] = p[i];
    };
    auto dswrite = [&](int buf) {
        char* base = wrow + buf * 16384;
        uint4 w0, w1;
        w0.x = pk_bf16(gx[0].x, gx[0].y); w0.y = pk_bf16(gx[0].z, gx[0].w);
        w0.z = pk_bf16(gx[1].x, gx[1].y); w0.w = pk_bf16(gx[1].z, gx[1].w);
        w1.x = pk_bf16(gx[2].x, gx[2].y); w1.y = pk_bf16(gx[2].z, gx[2].w);
        w1.z = pk_bf16(gx[3].x, gx[3].y); w1.w = pk_bf16(gx[3].z, gx[3].w);
        *(uint4*)(base + woff0) = w0;
        *(uint4*)(base + woff1) = w1;
    };

    // ---- B fragment bases (frag idx = kstep*16 + wc*4 + n; 512 ushorts/frag)
    const unsigned short* bhp = Bhi + ((size_t)(wc * 4) * 64 + lane) * 8;
    const unsigned short* blp = Blo + ((size_t)(wc * 4) * 64 + lane) * 8;

    // ---- A fragment addressing
    const int arow_l = lane & 15;
    const int akg    = (lane >> 4) * 16;       // byte offset of 8-bf16 k-group

    f32x4 acc[4][4];
#pragma unroll
    for (int m = 0; m < 4; ++m)
#pragma unroll
        for (int n = 0; n < 4; ++n) acc[m][n] = f32x4{0.f, 0.f, 0.f, 0.f};

    auto body = [&](int t) {
        // 1) B loads for BOTH k-steps (dual reg sets: no WAR between k-steps)
        const unsigned short* bh0p = bhp + (size_t)(2 * t) * 8192;
        const unsigned short* bl0p = blp + (size_t)(2 * t) * 8192;
        const unsigned short* bh1p = bhp + (size_t)(2 * t + 1) * 8192;
        const unsigned short* bl1p = blp + (size_t)(2 * t + 1) * 8192;
        bf16x8 b0h[4], b0l[4], b1h[4], b1l[4];
#pragma unroll
        for (int n = 0; n < 4; ++n) {
            b0h[n] = *(const bf16x8*)(bh0p + n * 512);
            b0l[n] = *(const bf16x8*)(bl0p + n * 512);
            b1h[n] = *(const bf16x8*)(bh1p + n * 512);
            b1l[n] = *(const bf16x8*)(bl1p + n * 512);
        }
        // 2) two MFMA k-steps from LDS buf t&1
        const char* ab = (const char*)lds_raw + (t & 1) * 16384;
        __builtin_amdgcn_s_setprio(1);
#pragma unroll
        for (int kk = 0; kk < 2; ++kk) {
            const bf16x8* BH = kk ? b1h : b0h;
            const bf16x8* BL = kk ? b1l : b0l;
            bf16x8 af[4];
#pragma unroll
            for (int q = 0; q < 4; ++q) {
                const int arow = wr * 64 + q * 16 + arow_l;
                af[q] = *(const bf16x8*)(ab + arow * 128 + ((kk * 64 + akg) ^ ((arow & 7) << 4)));
            }
#pragma unroll
            for (int n = 0; n < 4; ++n)
#pragma unroll
                for (int q = 0; q < 4; ++q)
                    acc[q][n] = __builtin_amdgcn_mfma_f32_16x16x32_bf16(af[q], BH[n], acc[q][n], 0, 0, 0);
#pragma unroll
            for (int n = 0; n < 4; ++n)
#pragma unroll
                for (int q = 0; q < 4; ++q)
                    acc[q][n] = __builtin_amdgcn_mfma_f32_16x16x32_bf16(af[q], BL[n], acc[q][n], 0, 0, 0);
        }
        __builtin_amdgcn_s_setprio(0);
        // 3) stage x(t+1) (loaded last iter, long complete), refill gx
        if (t < NT - 1) {
            dswrite((t + 1) & 1);
            if (t + 2 < NT) issueX(t + 2);
            BARRIER_LGKM();
        }
    };

    // prologue: x(0) -> LDS buf0; x(1) -> gx (stays in flight across barrier)
    issueX(0);
    dswrite(0);
    issueX(1);
    BARRIER_LGKM();

    for (int t = 0; t < NT; ++t) body(t);

    // =========== epilogue: SiLU in-register, logits, flash-pool ===========
    float* a_red  = (float*)lds_raw;            // [4][128]  2 KB
    float* a_vals = (float*)(lds_raw + 2048);   // [128]     512 B
    float* redm   = (float*)(lds_raw + 2560);   // [8]
    float* bc2    = (float*)(lds_raw + 2592);   // [2]
    float* pp     = (float*)(lds_raw + 2688);   // [2][256]  2 KB

    const int rg = lane >> 4;
    float bpc[4], wac[4];
#pragma unroll
    for (int n = 0; n < 4; ++n) {
        int col = wc * 64 + n * 16 + (lane & 15);
        bpc[n] = bp[col];
        wac[n] = Wa[col];
    }

    // SiLU (overwrite acc with h, fp32) + per-row attention-logit partials
    float pa[16];
#pragma unroll
    for (int i = 0; i < 16; ++i) pa[i] = 0.f;
#pragma unroll
    for (int m = 0; m < 4; ++m)
#pragma unroll
        for (int n = 0; n < 4; ++n)
#pragma unroll
            for (int j = 0; j < 4; ++j) {
                float v  = acc[m][n][j] + bpc[n];
                float hh = v / (1.f + __expf(-v));
                acc[m][n][j] = hh;
                pa[m * 4 + j] = fmaf(hh, wac[n], pa[m * 4 + j]);
            }
    // reduce pa over the 16 lanes sharing each row
#pragma unroll
    for (int i = 0; i < 16; ++i) {
#pragma unroll
        for (int off = 1; off < 16; off <<= 1)
            pa[i] += __shfl_xor(pa[i], off, 64);
    }
    __syncthreads();          // K-loop LDS reads done before overlay writes
    if ((lane & 15) == 0) {
#pragma unroll
        for (int m = 0; m < 4; ++m)
#pragma unroll
            for (int j = 0; j < 4; ++j)
                a_red[wc * BM + wr * 64 + m * 16 + rg * 4 + j] = pa[m * 4 + j];
    }
    __syncthreads();
    if (tid < BM) {
        float av = a_red[tid] + a_red[BM + tid] + a_red[2 * BM + tid] + a_red[3 * BM + tid] + ba[0];
        a_vals[tid] = (lrow0 + tid < len) ? av : -3e38f;   // mask invalid rows
    }
    __syncthreads();

    // m_t = max over valid rows
    float mv = (tid < BM) ? a_vals[tid] : -3e38f;
    mv = wave_reduce_max(mv);
    if (lane == 0) redm[wave] = mv;
    __syncthreads();
    if (tid == 0) {
        float m = redm[0];
#pragma unroll
        for (int w = 1; w < 8; ++w) m = fmaxf(m, redm[w]);
        bc2[0] = m;
    }
    __syncthreads();
    const float m_t = bc2[0];

    // l_t = sum exp(a - m_t) over valid rows
    float es = (tid < BM) ? __expf(a_vals[tid] - m_t) : 0.f;
    es = wave_reduce_sum(es);
    if (lane == 0) redm[wave] = es;
    __syncthreads();
    float l_t = 0.f;
    if (tid == 0) {
#pragma unroll
        for (int w = 0; w < 8; ++w) l_t += redm[w];
    }

    // pooled partial: pp[c] = sum_rows exp(a-m_t) * h[row][c]  (h fp32 in acc)
    float ev[16];
    const int rbase = wr * 64 + rg * 4;
#pragma unroll
    for (int m = 0; m < 4; ++m)
#pragma unroll
        for (int j = 0; j < 4; ++j)
            ev[m * 4 + j] = __expf(a_vals[rbase + m * 16 + j] - m_t);
#pragma unroll
    for (int n = 0; n < 4; ++n) {
        float s = 0.f;
#pragma unroll
        for (int m = 0; m < 4; ++m)
#pragma unroll
            for (int j = 0; j < 4; ++j)
                s = fmaf(ev[m * 4 + j], acc[m][n][j], s);
        s += __shfl_xor(s, 16, 64);
        s += __shfl_xor(s, 32, 64);
        if (lane < 16) pp[wr * 256 + wc * 64 + n * 16 + lane] = s;
    }
    __syncthreads();

    const size_t pbase = ((size_t)bag * TPB + tile) * PSTRIDE;
    if (tid < 256) part[pbase + tid] = pp[tid] + pp[256 + tid];
    if (tid == 0) { part[pbase + 256] = m_t; part[pbase + 257] = l_t; }
}

// ---------------------------------------------------------------------------
// final: one block per bag. Flash-combine the per-tile partials, then
// logits = pooled @ Wc + bc.
// ---------------------------------------------------------------------------
__global__ __launch_bounds__(256)
void final_kernel(const float* __restrict__ part, const int* __restrict__ lengths,
                  const float* __restrict__ Wc, const float* __restrict__ bc,
                  float* __restrict__ out)
{
    __shared__ float red0[4], red1[4];
    const int b = blockIdx.x;
    const int c = threadIdx.x;
    const int len = lengths[b];
    int nt = (len + BM - 1) / BM;
    if (nt > TPB) nt = TPB;

    float mg = -3e38f;
    for (int t = 0; t < nt; ++t)
        mg = fmaxf(mg, part[((size_t)b * TPB + t) * PSTRIDE + 256]);

    float W = 0.f, pooled = 0.f;
    for (int t = 0; t < nt; ++t) {
        const size_t pb = ((size_t)b * TPB + t) * PSTRIDE;
        float sc = __expf(part[pb + 256] - mg);
        W      = fmaf(sc, part[pb + 257], W);
        pooled = fmaf(sc, part[pb + c],  pooled);
    }
    pooled /= W;

    const float wc0 = Wc[c * NC + 0], wc1 = Wc[c * NC + 1];
    const int wave = threadIdx.x >> 6, lane = threadIdx.x & 63;
    float l0 = wave_reduce_sum(pooled * wc0);
    float l1 = wave_reduce_sum(pooled * wc1);
    if (lane == 0) { red0[wave] = l0; red1[wave] = l1; }
    __syncthreads();
    if (threadIdx.x == 0) {
        out[b * NC + 0] = red0[0] + red0[1] + red0[2] + red0[3] + bc[0];
        out[b * NC + 1] = red1[0] + red1[1] + red1[2] + red1[3] + bc[1];
    }
}

extern "C" void kernel_launch(void* const* d_in, const int* in_sizes, int n_in,
                              void* d_out, int out_size, void* d_ws, size_t ws_size,
                              hipStream_t stream)
{
    const float* x       = (const float*)d_in[0];
    const int*   lengths = (const int*)d_in[1];
    const float* Wp      = (const float*)d_in[2];
    const float* bp      = (const float*)d_in[3];
    const float* Wa      = (const float*)d_in[4];
    const float* ba      = (const float*)d_in[5];
    const float* Wc      = (const float*)d_in[6];
    const float* bc      = (const float*)d_in[7];
    float* out = (float*)d_out;

    // workspace layout
    unsigned short* whi = (unsigned short*)d_ws;              // 512 KB
    unsigned short* wlo = whi + 262144;                       // 512 KB
    float* part = (float*)(wlo + 262144);                     // 8*64*260 f = 532 KB

    pack_kernel<<<128, 256, 0, stream>>>(Wp, whi, wlo);
    gemm_kernel<<<M_ALL / BM, 512, 0, stream>>>(x, whi, wlo, bp, Wa, ba, lengths, part);
    final_kernel<<<NB, 256, 0, stream>>>(part, lengths, Wc, bc, out);
}

// Round 16
// 105.306 us; speedup vs baseline: 3.7263x; 3.7263x over previous
//
#include <hip/hip_runtime.h>
#include <hip/hip_bf16.h>
#include <math.h>

#define NB 8
#define NN 8192
#define ND 1024
#define NH 256
#define NC 2
#define M_ALL (NB * NN)   // 65536 rows
#define BM 128            // block tile rows
#define TPB 64            // tiles per bag (8192/128)
#define BK 64             // K per iteration (2 MFMA k-steps)
#define NT (ND / BK)      // 16 iterations
#define PSTRIDE 260       // per-tile partial: 256 pooled + m_t + l_t (+pad)

typedef __attribute__((ext_vector_type(8))) short bf16x8;
typedef __attribute__((ext_vector_type(4))) float f32x4;

// barrier WITHOUT the compiler's vmcnt(0) drain: LDS ordering only.
#define BARRIER_LGKM() asm volatile("s_waitcnt lgkmcnt(0)\n\ts_barrier" ::: "memory")

__device__ inline unsigned short f2bf(float f) {   // RNE float -> bf16 bits
    unsigned int u = __builtin_bit_cast(unsigned int, f);
    u += 0x7FFFu + ((u >> 16) & 1u);
    return (unsigned short)(u >> 16);
}
__device__ inline float bf2f(unsigned short s) {
    unsigned int u = ((unsigned int)s) << 16;
    return __builtin_bit_cast(float, u);
}
__device__ inline unsigned int pk_bf16(float a, float b) {  // low=a, high=b
    __hip_bfloat162 t = __float22bfloat162_rn(float2{a, b});
    unsigned int r;
    __builtin_memcpy(&r, &t, 4);
    return r;
}

__device__ inline float wave_reduce_sum(float v) {
#pragma unroll
    for (int off = 32; off > 0; off >>= 1) v += __shfl_down(v, off, 64);
    return v;
}
__device__ inline float wave_reduce_max(float v) {
#pragma unroll
    for (int off = 32; off > 0; off >>= 1) v = fmaxf(v, __shfl_down(v, off, 64));
    return v;
}

// ---------------------------------------------------------------------------
// Pack Wp into bf16 hi/lo, MFMA-B-fragment-contiguous:
// frag (t = kstep 0..31, f = col-frag 0..15), lane l holds
// B[k = t*32 + (l>>4)*8 + j][col = f*16 + (l&15)], j=0..7 contiguous.
// ---------------------------------------------------------------------------
__global__ void pack_kernel(const float* __restrict__ Wp,
                            unsigned short* __restrict__ hi,
                            unsigned short* __restrict__ lo)
{
    int idx  = blockIdx.x * 256 + threadIdx.x;   // 0..32767
    int lane = idx & 63;
    int f    = (idx >> 6) & 15;
    int t    = idx >> 10;
    int col  = f * 16 + (lane & 15);
    int k0   = t * 32 + (lane >> 4) * 8;
    size_t off = (size_t)idx * 8;
#pragma unroll
    for (int j = 0; j < 8; ++j) {
        float w = Wp[(size_t)(k0 + j) * NH + col];
        unsigned short h = f2bf(w);
        hi[off + j] = h;
        lo[off + j] = f2bf(w - bf2f(h));
    }
}

// ---------------------------------------------------------------------------
// Fused GEMM + SiLU + attention logit + flash-style tile pooling.
// BM=128 => grid 512 (~320 live after ragged exit) => 2 INDEPENDENT blocks
// per CU (32 KB LDS, ~190 regs/wave at launch_bounds(512,2)) -- one block's
// B-L2 waits and barrier skew hide under the other's MFMA bursts. Dual B
// register sets remove the per-k-step WAR hazard.
// R15 ERRATum: launch_bounds(512,4) capped regs at 64 VGPR -> 674 MB spill
// traffic; (512,2) gives the full budget (no spill) while occupancy comes
// from the small per-block footprint, not a compiler cap.
// Numerics identical: bf16 hi+lo W, x RNE-bf16, fp32 h pooling.
// ---------------------------------------------------------------------------
__global__ __launch_bounds__(512, 2)
void gemm_kernel(const float* __restrict__ x,
                 const unsigned short* __restrict__ Bhi,
                 const unsigned short* __restrict__ Blo,
                 const float* __restrict__ bp,
                 const float* __restrict__ Wa,
                 const float* __restrict__ ba,
                 const int* __restrict__ lengths,
                 float* __restrict__ part)
{
    __shared__ __align__(16) unsigned char lds_raw[32768];  // A dbuf 2x16KB; epilogue overlay

    const int tid  = threadIdx.x;
    const int wave = tid >> 6;
    const int lane = tid & 63;
    const int wr = wave >> 2;           // 0..1: 64-row group
    const int wc = wave & 3;            // 0..3: 64-col group
    const int blk = blockIdx.x;
    const size_t row0 = (size_t)blk * BM;

    // ragged early-exit
    const int bag   = blk >> 6;                // 64 tiles per bag
    const int tile  = blk & 63;
    const int lrow0 = tile * BM;
    const int len   = lengths[bag];
    if (lrow0 >= len) return;

    // ---- x staging: thread -> row (tid>>2), 16-float slot (tid&3)
    const int srow = tid >> 2;                 // 0..127
    const int slot = tid & 3;
    const float* xp = x + (row0 + srow) * ND + slot * 16;
    const int swz = (srow & 7) << 4;
    const int woff0 = (slot * 32) ^ swz;
    const int woff1 = (slot * 32 + 16) ^ swz;
    char* const wrow = (char*)lds_raw + srow * 128;

    float4 gx[4];                              // 16 VGPR, 1-iter lifetime
    auto issueX = [&](int t) {
        const float4* p = (const float4*)(xp + (size_t)t * BK);
#pragma unroll
        for (int i = 0; i < 4; ++i) gx[i] = p[i];
    };
    auto dswrite = [&](int buf) {
        char* base = wrow + buf * 16384;
        uint4 w0, w1;
        w0.x = pk_bf16(gx[0].x, gx[0].y); w0.y = pk_bf16(gx[0].z, gx[0].w);
        w0.z = pk_bf16(gx[1].x, gx[1].y); w0.w = pk_bf16(gx[1].z, gx[1].w);
        w1.x = pk_bf16(gx[2].x, gx[2].y); w1.y = pk_bf16(gx[2].z, gx[2].w);
        w1.z = pk_bf16(gx[3].x, gx[3].y); w1.w = pk_bf16(gx[3].z, gx[3].w);
        *(uint4*)(base + woff0) = w0;
        *(uint4*)(base + woff1) = w1;
    };

    // ---- B fragment bases (frag idx = kstep*16 + wc*4 + n; 512 ushorts/frag)
    const unsigned short* bhp = Bhi + ((size_t)(wc * 4) * 64 + lane) * 8;
    const unsigned short* blp = Blo + ((size_t)(wc * 4) * 64 + lane) * 8;

    // ---- A fragment addressing
    const int arow_l = lane & 15;
    const int akg    = (lane >> 4) * 16;       // byte offset of 8-bf16 k-group

    f32x4 acc[4][4];
#pragma unroll
    for (int m = 0; m < 4; ++m)
#pragma unroll
        for (int n = 0; n < 4; ++n) acc[m][n] = f32x4{0.f, 0.f, 0.f, 0.f};

    auto body = [&](int t) {
        // 1) B loads for BOTH k-steps (dual reg sets: no WAR between k-steps)
        const unsigned short* bh0p = bhp + (size_t)(2 * t) * 8192;
        const unsigned short* bl0p = blp + (size_t)(2 * t) * 8192;
        const unsigned short* bh1p = bhp + (size_t)(2 * t + 1) * 8192;
        const unsigned short* bl1p = blp + (size_t)(2 * t + 1) * 8192;
        bf16x8 b0h[4], b0l[4], b1h[4], b1l[4];
#pragma unroll
        for (int n = 0; n < 4; ++n) {
            b0h[n] = *(const bf16x8*)(bh0p + n * 512);
            b0l[n] = *(const bf16x8*)(bl0p + n * 512);
            b1h[n] = *(const bf16x8*)(bh1p + n * 512);
            b1l[n] = *(const bf16x8*)(bl1p + n * 512);
        }
        // 2) two MFMA k-steps from LDS buf t&1
        const char* ab = (const char*)lds_raw + (t & 1) * 16384;
        __builtin_amdgcn_s_setprio(1);
#pragma unroll
        for (int kk = 0; kk < 2; ++kk) {
            const bf16x8* BH = kk ? b1h : b0h;
            const bf16x8* BL = kk ? b1l : b0l;
            bf16x8 af[4];
#pragma unroll
            for (int q = 0; q < 4; ++q) {
                const int arow = wr * 64 + q * 16 + arow_l;
                af[q] = *(const bf16x8*)(ab + arow * 128 + ((kk * 64 + akg) ^ ((arow & 7) << 4)));
            }
#pragma unroll
            for (int n = 0; n < 4; ++n)
#pragma unroll
                for (int q = 0; q < 4; ++q)
                    acc[q][n] = __builtin_amdgcn_mfma_f32_16x16x32_bf16(af[q], BH[n], acc[q][n], 0, 0, 0);
#pragma unroll
            for (int n = 0; n < 4; ++n)
#pragma unroll
                for (int q = 0; q < 4; ++q)
                    acc[q][n] = __builtin_amdgcn_mfma_f32_16x16x32_bf16(af[q], BL[n], acc[q][n], 0, 0, 0);
        }
        __builtin_amdgcn_s_setprio(0);
        // 3) stage x(t+1) (loaded last iter, long complete), refill gx
        if (t < NT - 1) {
            dswrite((t + 1) & 1);
            if (t + 2 < NT) issueX(t + 2);
            BARRIER_LGKM();
        }
    };

    // prologue: x(0) -> LDS buf0; x(1) -> gx (stays in flight across barrier)
    issueX(0);
    dswrite(0);
    issueX(1);
    BARRIER_LGKM();

    for (int t = 0; t < NT; ++t) body(t);

    // =========== epilogue: SiLU in-register, logits, flash-pool ===========
    float* a_red  = (float*)lds_raw;            // [4][128]  2 KB
    float* a_vals = (float*)(lds_raw + 2048);   // [128]     512 B
    float* redm   = (float*)(lds_raw + 2560);   // [8]
    float* bc2    = (float*)(lds_raw + 2592);   // [2]
    float* pp     = (float*)(lds_raw + 2688);   // [2][256]  2 KB

    const int rg = lane >> 4;
    float bpc[4], wac[4];
#pragma unroll
    for (int n = 0; n < 4; ++n) {
        int col = wc * 64 + n * 16 + (lane & 15);
        bpc[n] = bp[col];
        wac[n] = Wa[col];
    }

    // SiLU (overwrite acc with h, fp32) + per-row attention-logit partials
    float pa[16];
#pragma unroll
    for (int i = 0; i < 16; ++i) pa[i] = 0.f;
#pragma unroll
    for (int m = 0; m < 4; ++m)
#pragma unroll
        for (int n = 0; n < 4; ++n)
#pragma unroll
            for (int j = 0; j < 4; ++j) {
                float v  = acc[m][n][j] + bpc[n];
                float hh = v / (1.f + __expf(-v));
                acc[m][n][j] = hh;
                pa[m * 4 + j] = fmaf(hh, wac[n], pa[m * 4 + j]);
            }
    // reduce pa over the 16 lanes sharing each row
#pragma unroll
    for (int i = 0; i < 16; ++i) {
#pragma unroll
        for (int off = 1; off < 16; off <<= 1)
            pa[i] += __shfl_xor(pa[i], off, 64);
    }
    __syncthreads();          // K-loop LDS reads done before overlay writes
    if ((lane & 15) == 0) {
#pragma unroll
        for (int m = 0; m < 4; ++m)
#pragma unroll
            for (int j = 0; j < 4; ++j)
                a_red[wc * BM + wr * 64 + m * 16 + rg * 4 + j] = pa[m * 4 + j];
    }
    __syncthreads();
    if (tid < BM) {
        float av = a_red[tid] + a_red[BM + tid] + a_red[2 * BM + tid] + a_red[3 * BM + tid] + ba[0];
        a_vals[tid] = (lrow0 + tid < len) ? av : -3e38f;   // mask invalid rows
    }
    __syncthreads();

    // m_t = max over valid rows
    float mv = (tid < BM) ? a_vals[tid] : -3e38f;
    mv = wave_reduce_max(mv);
    if (lane == 0) redm[wave] = mv;
    __syncthreads();
    if (tid == 0) {
        float m = redm[0];
#pragma unroll
        for (int w = 1; w < 8; ++w) m = fmaxf(m, redm[w]);
        bc2[0] = m;
    }
    __syncthreads();
    const float m_t = bc2[0];

    // l_t = sum exp(a - m_t) over valid rows
    float es = (tid < BM) ? __expf(a_vals[tid] - m_t) : 0.f;
    es = wave_reduce_sum(es);
    if (lane == 0) redm[wave] = es;
    __syncthreads();
    float l_t = 0.f;
    if (tid == 0) {
#pragma unroll
        for (int w = 0; w < 8; ++w) l_t += redm[w];
    }

    // pooled partial: pp[c] = sum_rows exp(a-m_t) * h[row][c]  (h fp32 in acc)
    float ev[16];
    const int rbase = wr * 64 + rg * 4;
#pragma unroll
    for (int m = 0; m < 4; ++m)
#pragma unroll
        for (int j = 0; j < 4; ++j)
            ev[m * 4 + j] = __expf(a_vals[rbase + m * 16 + j] - m_t);
#pragma unroll
    for (int n = 0; n < 4; ++n) {
        float s = 0.f;
#pragma unroll
        for (int m = 0; m < 4; ++m)
#pragma unroll
            for (int j = 0; j < 4; ++j)
                s = fmaf(ev[m * 4 + j], acc[m][n][j], s);
        s += __shfl_xor(s, 16, 64);
        s += __shfl_xor(s, 32, 64);
        if (lane < 16) pp[wr * 256 + wc * 64 + n * 16 + lane] = s;
    }
    __syncthreads();

    const size_t pbase = ((size_t)bag * TPB + tile) * PSTRIDE;
    if (tid < 256) part[pbase + tid] = pp[tid] + pp[256 + tid];
    if (tid == 0) { part[pbase + 256] = m_t; part[pbase + 257] = l_t; }
}

// ---------------------------------------------------------------------------
// final: one block per bag. Flash-combine the per-tile partials, then
// logits = pooled @ Wc + bc.
// ---------------------------------------------------------------------------
__global__ __launch_bounds__(256)
void final_kernel(const float* __restrict__ part, const int* __restrict__ lengths,
                  const float* __restrict__ Wc, const float* __restrict__ bc,
                  float* __restrict__ out)
{
    __shared__ float red0[4], red1[4];
    const int b = blockIdx.x;
    const int c = threadIdx.x;
    const int len = lengths[b];
    int nt = (len + BM - 1) / BM;
    if (nt > TPB) nt = TPB;

    float mg = -3e38f;
    for (int t = 0; t < nt; ++t)
        mg = fmaxf(mg, part[((size_t)b * TPB + t) * PSTRIDE + 256]);

    float W = 0.f, pooled = 0.f;
    for (int t = 0; t < nt; ++t) {
        const size_t pb = ((size_t)b * TPB + t) * PSTRIDE;
        float sc = __expf(part[pb + 256] - mg);
        W      = fmaf(sc, part[pb + 257], W);
        pooled = fmaf(sc, part[pb + c],  pooled);
    }
    pooled /= W;

    const float wc0 = Wc[c * NC + 0], wc1 = Wc[c * NC + 1];
    const int wave = threadIdx.x >> 6, lane = threadIdx.x & 63;
    float l0 = wave_reduce_sum(pooled * wc0);
    float l1 = wave_reduce_sum(pooled * wc1);
    if (lane == 0) { red0[wave] = l0; red1[wave] = l1; }
    __syncthreads();
    if (threadIdx.x == 0) {
        out[b * NC + 0] = red0[0] + red0[1] + red0[2] + red0[3] + bc[0];
        out[b * NC + 1] = red1[0] + red1[1] + red1[2] + red1[3] + bc[1];
    }
}

extern "C" void kernel_launch(void* const* d_in, const int* in_sizes, int n_in,
                              void* d_out, int out_size, void* d_ws, size_t ws_size,
                              hipStream_t stream)
{
    const float* x       = (const float*)d_in[0];
    const int*   lengths = (const int*)d_in[1];
    const float* Wp      = (const float*)d_in[2];
    const float* bp      = (const float*)d_in[3];
    const float* Wa      = (const float*)d_in[4];
    const float* ba      = (const float*)d_in[5];
    const float* Wc      = (const float*)d_in[6];
    const float* bc      = (const float*)d_in[7];
    float* out = (float*)d_out;

    // workspace layout
    unsigned short* whi = (unsigned short*)d_ws;              // 512 KB
    unsigned short* wlo = whi + 262144;                       // 512 KB
    float* part = (float*)(wlo + 262144);                     // 8*64*260 f = 532 KB

    pack_kernel<<<128, 256, 0, stream>>>(Wp, whi, wlo);
    gemm_kernel<<<M_ALL / BM, 512, 0, stream>>>(x, whi, wlo, bp, Wa, ba, lengths, part);
    final_kernel<<<NB, 256, 0, stream>>>(part, lengths, Wc, bc, out);
}

// Round 18
// 100.399 us; speedup vs baseline: 3.9084x; 1.0489x over previous
//
#include <hip/hip_runtime.h>
#include <hip/hip_bf16.h>
#include <math.h>

#define NB 8
#define NN 8192
#define ND 1024
#define NH 256
#define NC 2
#define M_ALL (NB * NN)   // 65536 rows
#define BM 256            // block tile rows
#define BK 64             // K per iteration (4 MFMA k-steps of 16)
#define NT (ND / BK)      // 16 iterations
#define PSTRIDE 260       // per-tile partial: 256 pooled + m_t + l_t (+pad)

typedef __attribute__((ext_vector_type(8))) short bf16x8;
typedef __attribute__((ext_vector_type(16))) float f32x16;

// barrier WITHOUT the compiler's vmcnt(0) drain: LDS ordering only.
#define BARRIER_LGKM() asm volatile("s_waitcnt lgkmcnt(0)\n\ts_barrier" ::: "memory")

__device__ inline unsigned short f2bf(float f) {   // RNE float -> bf16 bits
    unsigned int u = __builtin_bit_cast(unsigned int, f);
    u += 0x7FFFu + ((u >> 16) & 1u);
    return (unsigned short)(u >> 16);
}
__device__ inline float bf2f(unsigned short s) {
    unsigned int u = ((unsigned int)s) << 16;
    return __builtin_bit_cast(float, u);
}
__device__ inline unsigned int pk_bf16(float a, float b) {  // low=a, high=b
    __hip_bfloat162 t = __float22bfloat162_rn(float2{a, b});
    unsigned int r;
    __builtin_memcpy(&r, &t, 4);
    return r;
}

__device__ inline float wave_reduce_sum(float v) {
#pragma unroll
    for (int off = 32; off > 0; off >>= 1) v += __shfl_down(v, off, 64);
    return v;
}
__device__ inline float wave_reduce_max(float v) {
#pragma unroll
    for (int off = 32; off > 0; off >>= 1) v = fmaxf(v, __shfl_down(v, off, 64));
    return v;
}

// ---------------------------------------------------------------------------
// Pack Wp into bf16 hi/lo for 32x32x16 MFMA B-fragments:
// frag (ks = kstep 0..63, f = col-frag 0..7), lane l holds
// B[k = ks*16 + (l>>5)*8 + j][col = f*32 + (l&31)], j=0..7 contiguous.
// (Any internal HW k-permutation cancels: A-read uses the same mapping.)
// ---------------------------------------------------------------------------
__global__ void pack_kernel(const float* __restrict__ Wp,
                            unsigned short* __restrict__ hi,
                            unsigned short* __restrict__ lo)
{
    int idx  = blockIdx.x * 256 + threadIdx.x;   // 0..32767
    int lane = idx & 63;
    int f    = (idx >> 6) & 7;
    int ks   = idx >> 9;
    int col  = f * 32 + (lane & 31);
    int k0   = ks * 16 + (lane >> 5) * 8;
    size_t off = (size_t)idx * 8;
#pragma unroll
    for (int j = 0; j < 8; ++j) {
        float w = Wp[(size_t)(k0 + j) * NH + col];
        unsigned short h = f2bf(w);
        hi[off + j] = h;
        lo[off + j] = f2bf(w - bf2f(h));
    }
}

// ---------------------------------------------------------------------------
// Fused GEMM + SiLU + attention logit + flash-style tile pooling.
// R13 skeleton (256x256 tile, 8 waves 2x4, BK=64, gx depth-2 x staging,
// lgkm-only barriers, in-register flash epilogue) with:
//  * 32x32x16 MFMA: 2x FLOP/operand-byte (B L1 traffic halves), ~17% faster
//    matrix pipe, A-frag ds_reads halve.
//  * dual rotating B reg sets: B(ks+1) issued during MFMA(ks) (~1030 cyc
//    cover > L2 latency) -- no per-k-step WAR stall (R13's residual).
// R17 BUG FIXED: issueX(t+2) was clobbering gx BEFORE dswrite(t+1) consumed
// it (LDS got tile t+2 where t+1 belonged). Order is now mfma -> dswrite ->
// issueX -> barrier, exactly as R13.
// Regs: 128 acc + 32 B + 32 gx + 16 af + addr ~ 228 < 256 (no spill).
// ---------------------------------------------------------------------------
__global__ __launch_bounds__(512, 1)
void gemm_kernel(const float* __restrict__ x,
                 const unsigned short* __restrict__ Bhi,
                 const unsigned short* __restrict__ Blo,
                 const float* __restrict__ bp,
                 const float* __restrict__ Wa,
                 const float* __restrict__ ba,
                 const int* __restrict__ lengths,
                 float* __restrict__ part)
{
    __shared__ __align__(16) unsigned char lds_raw[65536];  // A dbuf 2x32KB; epilogue overlay

    const int tid  = threadIdx.x;
    const int wave = tid >> 6;
    const int lane = tid & 63;
    const int wr = wave >> 2;           // 0..1: 128-row group
    const int wc = wave & 3;            // 0..3: 64-col group
    const int hi = lane >> 5;           // 0..1 (32-lane half)
    const int cl = lane & 31;
    const int blk = blockIdx.x;
    const size_t row0 = (size_t)blk * BM;

    // ragged early-exit
    const int bag   = blk >> 5;                // 32 tiles per bag
    const int tile  = blk & 31;
    const int lrow0 = tile * BM;
    const int len   = lengths[bag];
    if (lrow0 >= len) return;

    // ---- x staging: thread -> row (tid>>1), 32-float half (tid&1)
    const int srow = tid >> 1;                 // 0..255
    const int shalf = tid & 1;
    const float* xp = x + (row0 + srow) * ND + shalf * 32;
    const int swz = (srow & 7) << 4;
    int woff[4];
#pragma unroll
    for (int q = 0; q < 4; ++q) woff[q] = (shalf * 64 + q * 16) ^ swz;
    char* const wrow = (char*)lds_raw + srow * 128;

    float4 gx[8];                              // 32 VGPR, ~1-iter lifetime
    auto issueX = [&](int t) {
        const float4* p = (const float4*)(xp + (size_t)t * BK);
#pragma unroll
        for (int i = 0; i < 8; ++i) gx[i] = p[i];
    };
    auto dswrite = [&](int buf) {
        char* base = wrow + buf * 32768;
#pragma unroll
        for (int q = 0; q < 4; ++q) {
            uint4 w;
            w.x = pk_bf16(gx[2 * q].x,     gx[2 * q].y);
            w.y = pk_bf16(gx[2 * q].z,     gx[2 * q].w);
            w.z = pk_bf16(gx[2 * q + 1].x, gx[2 * q + 1].y);
            w.w = pk_bf16(gx[2 * q + 1].z, gx[2 * q + 1].w);
            *(uint4*)(base + woff[q]) = w;
        }
    };

    // ---- B fragment bases: frag idx = ks*8 + wc*2 + nf; 512 ushorts/frag
    const unsigned short* bhp = Bhi + ((size_t)(wc * 2) * 64 + lane) * 8;
    const unsigned short* blp = Blo + ((size_t)(wc * 2) * 64 + lane) * 8;

    bf16x8 s0h[2], s0l[2], s1h[2], s1l[2];     // dual rotating B sets
    auto loadB0 = [&](int ks) {
        const unsigned short* h = bhp + (size_t)ks * 4096;
        const unsigned short* l = blp + (size_t)ks * 4096;
        s0h[0] = *(const bf16x8*)(h);       s0h[1] = *(const bf16x8*)(h + 512);
        s0l[0] = *(const bf16x8*)(l);       s0l[1] = *(const bf16x8*)(l + 512);
    };
    auto loadB1 = [&](int ks) {
        const unsigned short* h = bhp + (size_t)ks * 4096;
        const unsigned short* l = blp + (size_t)ks * 4096;
        s1h[0] = *(const bf16x8*)(h);       s1h[1] = *(const bf16x8*)(h + 512);
        s1l[0] = *(const bf16x8*)(l);       s1l[1] = *(const bf16x8*)(l + 512);
    };

    f32x16 acc[4][2];
#pragma unroll
    for (int m = 0; m < 4; ++m)
#pragma unroll
        for (int n = 0; n < 2; ++n)
#pragma unroll
            for (int j = 0; j < 16; ++j) acc[m][n][j] = 0.f;

    auto mfma_ks = [&](int kk, const bf16x8 (&BH)[2], const bf16x8 (&BL)[2], const char* ab) {
        bf16x8 af[4];
#pragma unroll
        for (int mq = 0; mq < 4; ++mq) {
            const int arow = wr * 128 + mq * 32 + cl;
            af[mq] = *(const bf16x8*)(ab + arow * 128 + ((kk * 32 + hi * 16) ^ ((arow & 7) << 4)));
        }
        __builtin_amdgcn_s_setprio(1);
#pragma unroll
        for (int mq = 0; mq < 4; ++mq)
#pragma unroll
            for (int nf = 0; nf < 2; ++nf)
                acc[mq][nf] = __builtin_amdgcn_mfma_f32_32x32x16_bf16(af[mq], BH[nf], acc[mq][nf], 0, 0, 0);
#pragma unroll
        for (int mq = 0; mq < 4; ++mq)
#pragma unroll
            for (int nf = 0; nf < 2; ++nf)
                acc[mq][nf] = __builtin_amdgcn_mfma_f32_32x32x16_bf16(af[mq], BL[nf], acc[mq][nf], 0, 0, 0);
        __builtin_amdgcn_s_setprio(0);
    };

    // prologue: x(0) -> LDS buf0; B(ks=0) -> set0; x(1) in flight
    issueX(0);
    dswrite(0);          // waits only x(0)
    loadB0(0);
    issueX(1);
    BARRIER_LGKM();

    for (int t = 0; t < NT; ++t) {
        const char* ab = (const char*)lds_raw + (t & 1) * 32768;
        const int ks0 = 4 * t;
        // kk0: consume S0(ks0), prefetch S1(ks0+1)
        loadB1(ks0 + 1);
        mfma_ks(0, s0h, s0l, ab);
        // kk1: consume S1, prefetch S0(ks0+2)
        loadB0(ks0 + 2);
        mfma_ks(1, s1h, s1l, ab);
        // kk2: consume S0, prefetch S1(ks0+3)
        loadB1(ks0 + 3);
        mfma_ks(2, s0h, s0l, ab);
        // kk3: prefetch S0(next iter), consume S1
        if (t < NT - 1) loadB0(ks0 + 4);
        mfma_ks(3, s1h, s1l, ab);
        // tail (R13 order): stage x(t+1) from gx, THEN refill gx with x(t+2)
        if (t < NT - 1) {
            dswrite((t + 1) & 1);
            if (t + 2 < NT) issueX(t + 2);
            BARRIER_LGKM();
        }
    }

    // =========== epilogue: SiLU in-register, logits, flash-pool ===========
    // C layout (32x32, m74/m101): col = cl, row_local = (j&3)+8*(j>>2)+4*hi
    float* a_red  = (float*)lds_raw;            // [4][256]  4 KB (later e_lds)
    float* a_vals = (float*)(lds_raw + 4096);   // [256]     1 KB
    float* redm   = (float*)(lds_raw + 5120);   // [8]
    float* bc2    = (float*)(lds_raw + 5152);   // [2]
    float* pp     = (float*)(lds_raw + 5248);   // [2][256]  2 KB

    float bpc[2], wac[2];
#pragma unroll
    for (int nf = 0; nf < 2; ++nf) {
        int col = wc * 64 + nf * 32 + cl;
        bpc[nf] = bp[col];
        wac[nf] = Wa[col];
    }

    // SiLU (overwrite acc with h, fp32) + per-row attention-logit partials
    float pa[4][16];
#pragma unroll
    for (int m = 0; m < 4; ++m)
#pragma unroll
        for (int j = 0; j < 16; ++j) pa[m][j] = 0.f;
#pragma unroll
    for (int mq = 0; mq < 4; ++mq)
#pragma unroll
        for (int nf = 0; nf < 2; ++nf)
#pragma unroll
            for (int j = 0; j < 16; ++j) {
                float v  = acc[mq][nf][j] + bpc[nf];
                float hh = v / (1.f + __expf(-v));
                acc[mq][nf][j] = hh;
                pa[mq][j] = fmaf(hh, wac[nf], pa[mq][j]);
            }
    // reduce pa over the 32 lanes (cols) of each half
#pragma unroll
    for (int mq = 0; mq < 4; ++mq)
#pragma unroll
        for (int j = 0; j < 16; ++j) {
#pragma unroll
            for (int off = 1; off <= 16; off <<= 1)
                pa[mq][j] += __shfl_xor(pa[mq][j], off, 64);
        }
    __syncthreads();          // K-loop LDS reads done before overlay writes
    if (cl == 0) {            // lanes 0 and 32 write their hi-half rows
#pragma unroll
        for (int mq = 0; mq < 4; ++mq)
#pragma unroll
            for (int j = 0; j < 16; ++j) {
                int row = wr * 128 + mq * 32 + (j & 3) + 8 * (j >> 2) + 4 * hi;
                a_red[wc * BM + row] = pa[mq][j];
            }
    }
    __syncthreads();
    if (tid < BM) {
        float av = a_red[tid] + a_red[BM + tid] + a_red[2 * BM + tid] + a_red[3 * BM + tid] + ba[0];
        a_vals[tid] = (lrow0 + tid < len) ? av : -3e38f;   // mask invalid rows
    }
    __syncthreads();

    // m_t = max over valid rows
    float mv = (tid < BM) ? a_vals[tid] : -3e38f;
    mv = wave_reduce_max(mv);
    if (lane == 0) redm[wave] = mv;
    __syncthreads();
    if (tid == 0) {
        float m = redm[0];
#pragma unroll
        for (int w = 1; w < 8; ++w) m = fmaxf(m, redm[w]);
        bc2[0] = m;
    }
    __syncthreads();
    const float m_t = bc2[0];

    // l_t = sum exp(a - m_t); also cache e values in LDS (a_red reused)
    float* e_lds = a_red;
    float es0 = (tid < BM) ? __expf(a_vals[tid] - m_t) : 0.f;
    if (tid < BM) e_lds[tid] = es0;
    float es = wave_reduce_sum(es0);
    if (lane == 0) redm[wave] = es;
    __syncthreads();
    float l_t = 0.f;
    if (tid == 0) {
#pragma unroll
        for (int w = 0; w < 8; ++w) l_t += redm[w];
    }

    // pooled partial: pp[c] = sum_rows e[row] * h[row][c]  (h fp32 in acc)
    float s0 = 0.f, s1 = 0.f;
#pragma unroll
    for (int mq = 0; mq < 4; ++mq)
#pragma unroll
        for (int j = 0; j < 16; ++j) {
            int row = wr * 128 + mq * 32 + (j & 3) + 8 * (j >> 2) + 4 * hi;
            float e = e_lds[row];               // broadcast within hi-group
            s0 = fmaf(e, acc[mq][0][j], s0);
            s1 = fmaf(e, acc[mq][1][j], s1);
        }
    s0 += __shfl_xor(s0, 32, 64);               // combine the two row-halves
    s1 += __shfl_xor(s1, 32, 64);
    if (lane < 32) {
        pp[wr * 256 + wc * 64 + cl]      = s0;
        pp[wr * 256 + wc * 64 + 32 + cl] = s1;
    }
    __syncthreads();

    const size_t pbase = ((size_t)bag * 32 + tile) * PSTRIDE;
    if (tid < 256) part[pbase + tid] = pp[tid] + pp[256 + tid];
    if (tid == 0) { part[pbase + 256] = m_t; part[pbase + 257] = l_t; }
}

// ---------------------------------------------------------------------------
// final: one block per bag. Flash-combine the per-tile partials, then
// logits = pooled @ Wc + bc.
// ---------------------------------------------------------------------------
__global__ __launch_bounds__(256)
void final_kernel(const float* __restrict__ part, const int* __restrict__ lengths,
                  const float* __restrict__ Wc, const float* __restrict__ bc,
                  float* __restrict__ out)
{
    __shared__ float red0[4], red1[4];
    const int b = blockIdx.x;
    const int c = threadIdx.x;
    const int len = lengths[b];
    int nt = (len + BM - 1) / BM;
    if (nt > 32) nt = 32;

    float mg = -3e38f;
    for (int t = 0; t < nt; ++t)
        mg = fmaxf(mg, part[((size_t)b * 32 + t) * PSTRIDE + 256]);

    float W = 0.f, pooled = 0.f;
    for (int t = 0; t < nt; ++t) {
        const size_t pb = ((size_t)b * 32 + t) * PSTRIDE;
        float sc = __expf(part[pb + 256] - mg);
        W      = fmaf(sc, part[pb + 257], W);
        pooled = fmaf(sc, part[pb + c],  pooled);
    }
    pooled /= W;

    const float wc0 = Wc[c * NC + 0], wc1 = Wc[c * NC + 1];
    const int wave = threadIdx.x >> 6, lane = threadIdx.x & 63;
    float l0 = wave_reduce_sum(pooled * wc0);
    float l1 = wave_reduce_sum(pooled * wc1);
    if (lane == 0) { red0[wave] = l0; red1[wave] = l1; }
    __syncthreads();
    if (threadIdx.x == 0) {
        out[b * NC + 0] = red0[0] + red0[1] + red0[2] + red0[3] + bc[0];
        out[b * NC + 1] = red1[0] + red1[1] + red1[2] + red1[3] + bc[1];
    }
}

extern "C" void kernel_launch(void* const* d_in, const int* in_sizes, int n_in,
                              void* d_out, int out_size, void* d_ws, size_t ws_size,
                              hipStream_t stream)
{
    const float* x       = (const float*)d_in[0];
    const int*   lengths = (const int*)d_in[1];
    const float* Wp      = (const float*)d_in[2];
    const float* bp      = (const float*)d_in[3];
    const float* Wa      = (const float*)d_in[4];
    const float* ba      = (const float*)d_in[5];
    const float* Wc      = (const float*)d_in[6];
    const float* bc      = (const float*)d_in[7];
    float* out = (float*)d_out;

    // workspace layout
    unsigned short* whi = (unsigned short*)d_ws;              // 512 KB
    unsigned short* wlo = whi + 262144;                       // 512 KB
    float* part = (float*)(wlo + 262144);                     // 8*32*260 f = 260 KB

    pack_kernel<<<128, 256, 0, stream>>>(Wp, whi, wlo);
    gemm_kernel<<<M_ALL / BM, 512, 0, stream>>>(x, whi, wlo, bp, Wa, ba, lengths, part);
    final_kernel<<<NB, 256, 0, stream>>>(part, lengths, Wc, bc, out);
}

// Round 19
// 78.096 us; speedup vs baseline: 5.0245x; 1.2856x over previous
//
#include <hip/hip_runtime.h>
#include <hip/hip_bf16.h>
#include <math.h>

#define NB 8
#define NN 8192
#define ND 1024
#define NH 256
#define NC 2
#define M_ALL (NB * NN)   // 65536 rows
#define BM 256            // block tile rows
#define BK 64             // K per iteration (2 MFMA k-steps of 32)
#define NT (ND / BK)      // 16 iterations
#define PSTRIDE 260       // per-tile partial: 256 pooled + m_t + l_t (+pad)

typedef __attribute__((ext_vector_type(8))) short bf16x8;
typedef __attribute__((ext_vector_type(4))) float f32x4;

// barrier WITHOUT the compiler's vmcnt(0) drain: LDS ordering only.
#define BARRIER_LGKM() asm volatile("s_waitcnt lgkmcnt(0)\n\ts_barrier" ::: "memory")

__device__ inline unsigned short f2bf(float f) {   // RNE float -> bf16 bits
    unsigned int u = __builtin_bit_cast(unsigned int, f);
    u += 0x7FFFu + ((u >> 16) & 1u);
    return (unsigned short)(u >> 16);
}
__device__ inline float bf2f(unsigned short s) {
    unsigned int u = ((unsigned int)s) << 16;
    return __builtin_bit_cast(float, u);
}
__device__ inline unsigned int pk_bf16(float a, float b) {  // low=a, high=b
    __hip_bfloat162 t = __float22bfloat162_rn(float2{a, b});
    unsigned int r;
    __builtin_memcpy(&r, &t, 4);
    return r;
}

__device__ inline float wave_reduce_sum(float v) {
#pragma unroll
    for (int off = 32; off > 0; off >>= 1) v += __shfl_down(v, off, 64);
    return v;
}
__device__ inline float wave_reduce_max(float v) {
#pragma unroll
    for (int off = 32; off > 0; off >>= 1) v = fmaxf(v, __shfl_down(v, off, 64));
    return v;
}

// ---------------------------------------------------------------------------
// Pack Wp into bf16 (RNE), MFMA-B-fragment-contiguous (16x16x32):
// frag (t = kstep 0..31, f = col-frag 0..15), lane l holds
// B[k = t*32 + (l>>4)*8 + j][col = f*16 + (l&15)], j=0..7 contiguous.
// Single-precision W: R10 measured absmax identical to hi+lo (x-rounding
// dominates), so the lo correction term is provably removable.
// ---------------------------------------------------------------------------
__global__ void pack_kernel(const float* __restrict__ Wp,
                            unsigned short* __restrict__ hi)
{
    int idx  = blockIdx.x * 256 + threadIdx.x;   // 0..32767
    int lane = idx & 63;
    int f    = (idx >> 6) & 15;
    int t    = idx >> 10;
    int col  = f * 16 + (lane & 15);
    int k0   = t * 32 + (lane >> 4) * 8;
    size_t off = (size_t)idx * 8;
#pragma unroll
    for (int j = 0; j < 8; ++j)
        hi[off + j] = f2bf(Wp[(size_t)(k0 + j) * NH + col]);
}

// ---------------------------------------------------------------------------
// Fused GEMM + SiLU + attention logit + flash-style tile pooling.
// R13 skeleton (256x256 tile, 8 waves 2x4, BK=64, gx depth-2 x staging,
// lgkm-only barriers, in-register flash epilogue) with:
//  * single bf16 W (no lo term): MFMA work halves (floor 33 -> 16.5 us);
//    accuracy unchanged (R10-verified on this data).
//  * dual rotating B reg sets: B(ks+1) issued before MFMA(ks) (~1240 cyc
//    cover > L2 latency) -- removes R13's per-k-step WAR stall.
// Regs: 128 acc + 32 gx + 32 B + 16 af + addr ~ 233 < 256 (no spill).
// vmcnt FIFO: gx(t+1) is oldest; B sets middle; consuming an older B set
// leaves the newer one and nothing blocks gx staging.
// ---------------------------------------------------------------------------
__global__ __launch_bounds__(512, 2)
void gemm_kernel(const float* __restrict__ x,
                 const unsigned short* __restrict__ Bhi,
                 const float* __restrict__ bp,
                 const float* __restrict__ Wa,
                 const float* __restrict__ ba,
                 const int* __restrict__ lengths,
                 float* __restrict__ part)
{
    __shared__ __align__(16) unsigned char lds_raw[65536];  // A dbuf 2x32KB; epilogue overlay

    const int tid  = threadIdx.x;
    const int wave = tid >> 6;
    const int lane = tid & 63;
    const int wr = wave >> 2;           // 0..1: 128-row group
    const int wc = wave & 3;            // 0..3: 64-col group
    const int blk = blockIdx.x;
    const size_t row0 = (size_t)blk * BM;

    // ragged early-exit
    const int bag   = blk >> 5;                // 32 tiles per bag
    const int tile  = blk & 31;
    const int lrow0 = tile * BM;
    const int len   = lengths[bag];
    if (lrow0 >= len) return;

    // ---- x staging: thread -> row (tid>>1), 32-float half (tid&1)
    const int srow = tid >> 1;                 // 0..255
    const int shalf = tid & 1;
    const float* xp = x + (row0 + srow) * ND + shalf * 32;
    const int swz = (srow & 7) << 4;
    int woff[4];
#pragma unroll
    for (int q = 0; q < 4; ++q) woff[q] = (shalf * 64 + q * 16) ^ swz;
    char* const wrow = (char*)lds_raw + srow * 128;

    float4 gx[8];                              // 32 VGPR, 1-iter lifetime
    auto issueX = [&](int t) {
        const float4* p = (const float4*)(xp + (size_t)t * BK);
#pragma unroll
        for (int i = 0; i < 8; ++i) gx[i] = p[i];
    };
    auto dswrite = [&](int buf) {
        char* base = wrow + buf * 32768;
#pragma unroll
        for (int q = 0; q < 4; ++q) {
            uint4 w;
            w.x = pk_bf16(gx[2 * q].x,     gx[2 * q].y);
            w.y = pk_bf16(gx[2 * q].z,     gx[2 * q].w);
            w.z = pk_bf16(gx[2 * q + 1].x, gx[2 * q + 1].y);
            w.w = pk_bf16(gx[2 * q + 1].z, gx[2 * q + 1].w);
            *(uint4*)(base + woff[q]) = w;
        }
    };

    // ---- B fragment bases (frag idx = kstep*16 + wc*4 + n; 512 ushorts/frag)
    const unsigned short* bhp = Bhi + ((size_t)(wc * 4) * 64 + lane) * 8;

    bf16x8 s0[4], s1[4];                       // dual rotating B sets (32 VGPR)
    auto loadB0 = [&](int ks) {
        const unsigned short* h = bhp + (size_t)ks * 8192;
#pragma unroll
        for (int n = 0; n < 4; ++n) s0[n] = *(const bf16x8*)(h + n * 512);
    };
    auto loadB1 = [&](int ks) {
        const unsigned short* h = bhp + (size_t)ks * 8192;
#pragma unroll
        for (int n = 0; n < 4; ++n) s1[n] = *(const bf16x8*)(h + n * 512);
    };

    // ---- A fragment addressing
    const int arow_l = lane & 15;
    const int akg    = (lane >> 4) * 16;       // byte offset of 8-bf16 k-group

    f32x4 acc[8][4];
#pragma unroll
    for (int m = 0; m < 8; ++m)
#pragma unroll
        for (int n = 0; n < 4; ++n) acc[m][n] = f32x4{0.f, 0.f, 0.f, 0.f};

    auto mfma_ks = [&](int kk, const bf16x8 (&B)[4], const char* ab) {
        __builtin_amdgcn_s_setprio(1);
#pragma unroll
        for (int mm = 0; mm < 2; ++mm) {
            bf16x8 af[4];
#pragma unroll
            for (int q = 0; q < 4; ++q) {
                const int arow = wr * 128 + (mm * 4 + q) * 16 + arow_l;
                af[q] = *(const bf16x8*)(ab + arow * 128 + ((kk * 64 + akg) ^ ((arow & 7) << 4)));
            }
#pragma unroll
            for (int n = 0; n < 4; ++n)
#pragma unroll
                for (int q = 0; q < 4; ++q)
                    acc[mm * 4 + q][n] = __builtin_amdgcn_mfma_f32_16x16x32_bf16(af[q], B[n], acc[mm * 4 + q][n], 0, 0, 0);
        }
        __builtin_amdgcn_s_setprio(0);
    };

    // prologue: x(0) -> LDS buf0; B(ks=0) -> s0; x(1) in flight
    issueX(0);
    dswrite(0);          // waits only x(0)
    loadB0(0);
    issueX(1);
    BARRIER_LGKM();

    for (int t = 0; t < NT; ++t) {
        const char* ab = (const char*)lds_raw + (t & 1) * 32768;
        // kstep 2t (consumes s0): prefetch s1(2t+1) first
        loadB1(2 * t + 1);
        mfma_ks(0, s0, ab);
        // kstep 2t+1 (consumes s1): prefetch s0(2t+2) first
        if (t < NT - 1) loadB0(2 * t + 2);
        mfma_ks(1, s1, ab);
        // tail (R13 order): stage x(t+1) from gx, THEN refill gx with x(t+2)
        if (t < NT - 1) {
            dswrite((t + 1) & 1);
            if (t + 2 < NT) issueX(t + 2);
            BARRIER_LGKM();
        }
    }

    // =========== epilogue: SiLU in-register, logits, flash-pool ===========
    float* a_red  = (float*)lds_raw;            // [4][256]  4 KB
    float* a_vals = (float*)(lds_raw + 4096);   // [256]     1 KB
    float* redm   = (float*)(lds_raw + 5120);   // [8]
    float* bc2    = (float*)(lds_raw + 5152);   // [2]
    float* pp     = (float*)(lds_raw + 5248);   // [2][256]  2 KB

    const int rg = lane >> 4;
    float bpc[4], wac[4];
#pragma unroll
    for (int n = 0; n < 4; ++n) {
        int col = wc * 64 + n * 16 + (lane & 15);
        bpc[n] = bp[col];
        wac[n] = Wa[col];
    }

    // SiLU (overwrite acc with h, fp32) + per-row attention-logit partials
    float pa[32];
#pragma unroll
    for (int i = 0; i < 32; ++i) pa[i] = 0.f;
#pragma unroll
    for (int m = 0; m < 8; ++m)
#pragma unroll
        for (int n = 0; n < 4; ++n)
#pragma unroll
            for (int j = 0; j < 4; ++j) {
                float v  = acc[m][n][j] + bpc[n];
                float hh = v / (1.f + __expf(-v));
                acc[m][n][j] = hh;
                pa[m * 4 + j] = fmaf(hh, wac[n], pa[m * 4 + j]);
            }
    // reduce pa over the 16 lanes sharing each row
#pragma unroll
    for (int i = 0; i < 32; ++i) {
#pragma unroll
        for (int off = 1; off < 16; off <<= 1)
            pa[i] += __shfl_xor(pa[i], off, 64);
    }
    __syncthreads();          // K-loop LDS reads done before overlay writes
    if ((lane & 15) == 0) {
#pragma unroll
        for (int m = 0; m < 8; ++m)
#pragma unroll
            for (int j = 0; j < 4; ++j)
                a_red[wc * BM + wr * 128 + m * 16 + rg * 4 + j] = pa[m * 4 + j];
    }
    __syncthreads();
    if (tid < BM) {
        float av = a_red[tid] + a_red[BM + tid] + a_red[2 * BM + tid] + a_red[3 * BM + tid] + ba[0];
        a_vals[tid] = (lrow0 + tid < len) ? av : -3e38f;   // mask invalid rows
    }
    __syncthreads();

    // m_t = max over valid rows
    float mv = (tid < BM) ? a_vals[tid] : -3e38f;
    mv = wave_reduce_max(mv);
    if (lane == 0) redm[wave] = mv;
    __syncthreads();
    if (tid == 0) {
        float m = redm[0];
#pragma unroll
        for (int w = 1; w < 8; ++w) m = fmaxf(m, redm[w]);
        bc2[0] = m;
    }
    __syncthreads();
    const float m_t = bc2[0];

    // l_t = sum exp(a - m_t) over valid rows
    float es = (tid < BM) ? __expf(a_vals[tid] - m_t) : 0.f;
    es = wave_reduce_sum(es);
    if (lane == 0) redm[wave] = es;
    __syncthreads();
    float l_t = 0.f;
    if (tid == 0) {
#pragma unroll
        for (int w = 0; w < 8; ++w) l_t += redm[w];
    }

    // pooled partial: pp[c] = sum_rows exp(a-m_t) * h[row][c]  (h fp32 in acc)
    float ev[32];
    const int rbase = wr * 128 + rg * 4;
#pragma unroll
    for (int m = 0; m < 8; ++m)
#pragma unroll
        for (int j = 0; j < 4; ++j)
            ev[m * 4 + j] = __expf(a_vals[rbase + m * 16 + j] - m_t);
#pragma unroll
    for (int n = 0; n < 4; ++n) {
        float s = 0.f;
#pragma unroll
        for (int m = 0; m < 8; ++m)
#pragma unroll
            for (int j = 0; j < 4; ++j)
                s = fmaf(ev[m * 4 + j], acc[m][n][j], s);
        s += __shfl_xor(s, 16, 64);
        s += __shfl_xor(s, 32, 64);
        if (lane < 16) pp[wr * 256 + wc * 64 + n * 16 + lane] = s;
    }
    __syncthreads();

    const size_t pbase = ((size_t)bag * 32 + tile) * PSTRIDE;
    if (tid < BM) part[pbase + tid] = pp[tid] + pp[256 + tid];
    if (tid == 0) { part[pbase + 256] = m_t; part[pbase + 257] = l_t; }
}

// ---------------------------------------------------------------------------
// final: one block per bag. Flash-combine the per-tile partials, then
// logits = pooled @ Wc + bc.
// ---------------------------------------------------------------------------
__global__ __launch_bounds__(256)
void final_kernel(const float* __restrict__ part, const int* __restrict__ lengths,
                  const float* __restrict__ Wc, const float* __restrict__ bc,
                  float* __restrict__ out)
{
    __shared__ float red0[4], red1[4];
    const int b = blockIdx.x;
    const int c = threadIdx.x;
    const int len = lengths[b];
    int nt = (len + BM - 1) / BM;
    if (nt > 32) nt = 32;

    float mg = -3e38f;
    for (int t = 0; t < nt; ++t)
        mg = fmaxf(mg, part[((size_t)b * 32 + t) * PSTRIDE + 256]);

    float W = 0.f, pooled = 0.f;
    for (int t = 0; t < nt; ++t) {
        const size_t pb = ((size_t)b * 32 + t) * PSTRIDE;
        float sc = __expf(part[pb + 256] - mg);
        W      = fmaf(sc, part[pb + 257], W);
        pooled = fmaf(sc, part[pb + c],  pooled);
    }
    pooled /= W;

    const float wc0 = Wc[c * NC + 0], wc1 = Wc[c * NC + 1];
    const int wave = threadIdx.x >> 6, lane = threadIdx.x & 63;
    float l0 = wave_reduce_sum(pooled * wc0);
    float l1 = wave_reduce_sum(pooled * wc1);
    if (lane == 0) { red0[wave] = l0; red1[wave] = l1; }
    __syncthreads();
    if (threadIdx.x == 0) {
        out[b * NC + 0] = red0[0] + red0[1] + red0[2] + red0[3] + bc[0];
        out[b * NC + 1] = red1[0] + red1[1] + red1[2] + red1[3] + bc[1];
    }
}

extern "C" void kernel_launch(void* const* d_in, const int* in_sizes, int n_in,
                              void* d_out, int out_size, void* d_ws, size_t ws_size,
                              hipStream_t stream)
{
    const float* x       = (const float*)d_in[0];
    const int*   lengths = (const int*)d_in[1];
    const float* Wp      = (const float*)d_in[2];
    const float* bp      = (const float*)d_in[3];
    const float* Wa      = (const float*)d_in[4];
    const float* ba      = (const float*)d_in[5];
    const float* Wc      = (const float*)d_in[6];
    const float* bc      = (const float*)d_in[7];
    float* out = (float*)d_out;

    // workspace layout
    unsigned short* whi = (unsigned short*)d_ws;              // 512 KB
    float* part = (float*)(whi + 262144);                     // 8*32*260 f = 260 KB

    pack_kernel<<<128, 256, 0, stream>>>(Wp, whi);
    gemm_kernel<<<M_ALL / BM, 512, 0, stream>>>(x, whi, bp, Wa, ba, lengths, part);
    final_kernel<<<NB, 256, 0, stream>>>(part, lengths, Wc, bc, out);
}